// Round 18
// baseline (379.595 us; speedup 1.0000x reference)
//
#include <hip/hip_runtime.h>
#include <cstdint>
#include <cstddef>

#define SEQ_ 4096
#define DIM_ 1280
#define NHEAD_ 20
#define HDIM_ 64
#define FFN_ 5120
#define SEG_ 512
#define QKVN_ 3840

typedef __attribute__((ext_vector_type(8))) short bf16x8;
typedef __attribute__((ext_vector_type(4))) float f32x4;
typedef __attribute__((ext_vector_type(8))) unsigned short us8;
typedef __attribute__((ext_vector_type(4))) unsigned short us4;

__device__ __forceinline__ unsigned short f2b(float f) {
  unsigned int u = __builtin_bit_cast(unsigned int, f);
  u += 0x7fffu + ((u >> 16) & 1u);
  return (unsigned short)(u >> 16);
}

__device__ __forceinline__ float b2f(unsigned short u) {
  return __builtin_bit_cast(float, (unsigned int)u << 16);
}

__device__ __forceinline__ void gload_lds16(const void* g, void* l) {
  __builtin_amdgcn_global_load_lds(
      (const __attribute__((address_space(1))) unsigned int*)g,
      (__attribute__((address_space(3))) unsigned int*)l, 16, 0, 0);
}

#define WAITVM(N) asm volatile("s_waitcnt vmcnt(" #N ")" ::: "memory")

// ---------- batched: 6 weight transposes (f32->bf16) + LN1, one dispatch ----
__global__ __launch_bounds__(256) void transp_ln_kernel(
    const float* __restrict__ Wq, const float* __restrict__ Wk,
    const float* __restrict__ Wv, const float* __restrict__ Wo,
    const float* __restrict__ Wf1, const float* __restrict__ Wf2,
    unsigned short* __restrict__ Wqkvt, unsigned short* __restrict__ Wot,
    unsigned short* __restrict__ Wf1t, unsigned short* __restrict__ Wf2t,
    const float* __restrict__ hidden, const float* __restrict__ g1,
    const float* __restrict__ b1, unsigned short* __restrict__ xln) {
  int t = blockIdx.x;
  if (t >= 19200) {  // ---- LN1 row ----
    int row = t - 19200, tid = threadIdx.x;
    int l = tid & 63, w = tid >> 6;
    const float* x = hidden + (size_t)row * DIM_;
    float v[5], s = 0.f, s2 = 0.f;
#pragma unroll
    for (int i = 0; i < 5; ++i) {
      v[i] = x[tid + i * 256];
      s += v[i];
      s2 += v[i] * v[i];
    }
#pragma unroll
    for (int off = 1; off < 64; off <<= 1) {
      s += __shfl_xor(s, off);
      s2 += __shfl_xor(s2, off);
    }
    __shared__ float red[8];
    if (l == 0) { red[w * 2] = s; red[w * 2 + 1] = s2; }
    __syncthreads();
    s = red[0] + red[2] + red[4] + red[6];
    s2 = red[1] + red[3] + red[5] + red[7];
    float mu = s * (1.f / DIM_);
    float var = s2 * (1.f / DIM_) - mu * mu;
    float rs = rsqrtf(var + 1e-5f);
#pragma unroll
    for (int i = 0; i < 5; ++i) {
      int c = tid + i * 256;
      xln[(size_t)row * DIM_ + c] = f2b((v[i] - mu) * rs * g1[c] + b1[c]);
    }
    return;
  }
  // ---- transpose tile ----
  __shared__ float tile[32][33];
  const float* in;
  unsigned short* out;
  int R, C, bx, by;
  if (t < 6400) {
    int m = t / 1600, lt = t - m * 1600;
    in = (m == 0) ? Wq : (m == 1) ? Wk : (m == 2) ? Wv : Wo;
    out = (m < 3) ? Wqkvt + (size_t)m * DIM_ * DIM_ : Wot;
    R = DIM_; C = DIM_;
    bx = lt % 40; by = lt / 40;
  } else if (t < 12800) {
    int lt = t - 6400;
    in = Wf1; out = Wf1t; R = DIM_; C = FFN_;
    bx = lt % 160; by = lt / 160;
  } else {
    int lt = t - 12800;
    in = Wf2; out = Wf2t; R = FFN_; C = DIM_;
    bx = lt % 40; by = lt / 40;
  }
  int c0 = bx * 32, r0 = by * 32;
  int tx = threadIdx.x & 31, ty = threadIdx.x >> 5;
#pragma unroll
  for (int i = 0; i < 32; i += 8)
    tile[ty + i][tx] = in[(size_t)(r0 + ty + i) * C + c0 + tx];
  __syncthreads();
#pragma unroll
  for (int i = 0; i < 32; i += 8)
    out[(size_t)(c0 + ty + i) * R + r0 + tx] = f2b(tile[tx][ty + i]);
}

// ---------- 128x256 GEMM, BK=32, 8 waves, 3-buffer counted-vmcnt pipeline ----
// ROUND-12 KNOWN-GOOD structure (plateau: c ~= 1.6us per block-K-step,
// LDS-traffic-bound). (512,4) register ceiling; XOR swizzle -> 0 conflicts.
enum { EPI_QKV = 0, EPI_GELU = 3, EPI_PART = 4 };

template <int EPI>
__device__ __forceinline__ void gemm_body(
    const unsigned short* __restrict__ A, int lda,
    const unsigned short* __restrict__ Bt, int ldb,
    const float* __restrict__ bias, const float* __restrict__ bias2,
    void* __restrict__ out0, void* __restrict__ out1, void* __restrict__ out2,
    int M, int N, int K, int nz) {
  __shared__ char lds[3][24576];
  const int tid = threadIdx.x;
  const int l = tid & 63, w = tid >> 6;
  const int r16 = l & 15, kg4 = l >> 4;
  const int nx = gridDim.x;
  const int orig = blockIdx.y * nx + blockIdx.x;
  const int xcd = orig & 7, idx = orig >> 3;
  const int by = xcd * (gridDim.y >> 3) + idx / nx;
  const int bx = idx % nx;
  const int m0 = by * 128, n0 = bx * 256;
  const int wm = (w >> 2) * 64, wn = (w & 3) * 64;
  const int z = blockIdx.z;
  const int ntK = K >> 5;
  const int base = ntK / nz, rem = ntK % nz;
  const int k0 = z * base + (z < rem ? z : rem);
  const int nt = base + (z < rem ? 1 : 0);
  const int kc = (tid & 3) ^ ((tid >> 3) & 3);
  const unsigned short* aA = A + (size_t)(m0 + (tid >> 2)) * lda + kc * 8 + k0 * 32;
  const unsigned short* aB = Bt + (size_t)(n0 + (tid >> 2)) * ldb + kc * 8 + k0 * 32;
  const unsigned short* aB1 = aB + (size_t)128 * ldb;
  const int cswz = (kg4 ^ ((r16 >> 1) & 3)) << 4;
  int aoff[4], boff[4];
#pragma unroll
  for (int mi = 0; mi < 4; ++mi) aoff[mi] = (wm + mi * 16 + r16) * 64 + cswz;
#pragma unroll
  for (int ni = 0; ni < 4; ++ni) boff[ni] = 8192 + (wn + ni * 16 + r16) * 64 + cswz;

  f32x4 acc[4][4] = {};

#define STAGE(b, kt_)                                          \
  do {                                                         \
    const int kb = (kt_) * 32;                                 \
    char* dA = &lds[0][0] + (b) * 24576 + w * 1024;            \
    char* dB = dA + 8192;                                      \
    gload_lds16(aA + kb, dA);                                  \
    gload_lds16(aB + kb, dB);                                  \
    gload_lds16(aB1 + kb, dB + 8192);                          \
  } while (0)

  STAGE(0, 0);
  if (nt > 1) {
    STAGE(1, 1);
    WAITVM(3);
  } else {
    WAITVM(0);
  }
  __builtin_amdgcn_s_barrier();

  int cur = 0;
#pragma unroll 1
  for (int t = 0; t < nt; ++t) {
    if (t + 2 < nt) {
      int nxt = cur + 2; if (nxt >= 3) nxt -= 3;
      STAGE(nxt, t + 2);
    }
    const char* sl = &lds[0][0] + cur * 24576;
    bf16x8 af[4], bfv[4];
#pragma unroll
    for (int mi = 0; mi < 4; ++mi) af[mi] = *(const bf16x8*)(sl + aoff[mi]);
#pragma unroll
    for (int ni = 0; ni < 4; ++ni) bfv[ni] = *(const bf16x8*)(sl + boff[ni]);
    __builtin_amdgcn_s_setprio(1);
#pragma unroll
    for (int mi = 0; mi < 4; ++mi)
#pragma unroll
      for (int ni = 0; ni < 4; ++ni)
        acc[mi][ni] = __builtin_amdgcn_mfma_f32_16x16x32_bf16(af[mi], bfv[ni], acc[mi][ni], 0, 0, 0);
    __builtin_amdgcn_s_setprio(0);
    if (t + 2 < nt) WAITVM(3);
    else if (t + 1 < nt) WAITVM(0);
    if (t + 1 < nt) __builtin_amdgcn_s_barrier();
    ++cur; if (cur == 3) cur = 0;
  }
#undef STAGE

  const int rg = kg4 * 4;
#pragma unroll
  for (int mi = 0; mi < 4; ++mi) {
#pragma unroll
    for (int ni = 0; ni < 4; ++ni) {
      int row = m0 + wm + mi * 16 + rg;
      int col = n0 + wn + ni * 16 + r16;
      f32x4 v = acc[mi][ni];
      if constexpr (EPI == EPI_QKV) {
        if (col < DIM_) {  // Q (+bq)
          unsigned short* O = (unsigned short*)out0;
          float bb = bias[col];
#pragma unroll
          for (int j = 0; j < 4; ++j) O[(size_t)(row + j) * DIM_ + col] = f2b(v[j] + bb);
        } else if (col < 2 * DIM_) {  // K (no bias)
          unsigned short* O = (unsigned short*)out1;
          int cc = col - DIM_;
#pragma unroll
          for (int j = 0; j < 4; ++j) O[(size_t)(row + j) * DIM_ + cc] = f2b(v[j]);
        } else {  // V (+bv), transposed -> Vt[d][s]
          unsigned short* O = (unsigned short*)out2;
          int cc = col - 2 * DIM_;
          float bb = bias2[cc];
          us4 pk;
#pragma unroll
          for (int j = 0; j < 4; ++j) pk[j] = f2b(v[j] + bb);
          *(us4*)(O + (size_t)cc * SEQ_ + row) = pk;
        }
      } else if constexpr (EPI == EPI_GELU) {
        unsigned short* O = (unsigned short*)out0;
        float bb = bias[col];
#pragma unroll
        for (int j = 0; j < 4; ++j) {
          float t = v[j] + bb;
          t = 0.5f * t * (1.f + erff(t * 0.70710678118f));
          O[(size_t)(row + j) * N + col] = f2b(t);
        }
      } else {  // EPI_PART: bf16 partial per K-split
        unsigned short* O = (unsigned short*)out0 + (size_t)blockIdx.z * M * N;
#pragma unroll
        for (int j = 0; j < 4; ++j) O[(size_t)(row + j) * N + col] = f2b(v[j]);
      }
    }
  }
}

// distinct names for rocprof attribution
__global__ __launch_bounds__(512, 4) void qkv_gemm(
    const unsigned short* A, const unsigned short* Bt, const float* bq,
    const float* bv, void* q, void* k, void* v) {
  gemm_body<EPI_QKV>(A, DIM_, Bt, DIM_, bq, bv, q, k, v, SEQ_, QKVN_, DIM_, 1);
}
__global__ __launch_bounds__(512, 4) void wo_gemm(
    const unsigned short* A, const unsigned short* Bt, void* part) {
  gemm_body<EPI_PART>(A, DIM_, Bt, DIM_, nullptr, nullptr, part, nullptr, nullptr,
                      SEQ_, DIM_, DIM_, 3);
}
// ffn1 split-K=2: 1280 blocks x 20 steps (makespan 60 vs 80 at nz=1);
// bf16 partials alias the dead [xln..part3] span; GELU moves to reduce.
__global__ __launch_bounds__(512, 4) void ffn1_gemm(
    const unsigned short* A, const unsigned short* Bt, void* part) {
  gemm_body<EPI_PART>(A, DIM_, Bt, DIM_, nullptr, nullptr, part, nullptr, nullptr,
                      SEQ_, FFN_, DIM_, 2);
}
__global__ __launch_bounds__(512, 4) void ffn2_gemm(
    const unsigned short* A, const unsigned short* Bt, void* part) {
  gemm_body<EPI_PART>(A, FFN_, Bt, FFN_, nullptr, nullptr, part, nullptr, nullptr,
                      SEQ_, DIM_, FFN_, 3);
}

// ---------- ffn1 reduce: gbuf = gelu(p0 + p1 + bf1) (bf16 in/out) ----------
__global__ __launch_bounds__(256) void gelu_reduce2_kernel(
    const unsigned short* __restrict__ part, const float* __restrict__ bias,
    unsigned short* __restrict__ out) {
  const size_t MN = (size_t)SEQ_ * FFN_;
  for (size_t i = blockIdx.x * 256 + threadIdx.x; i * 4 < MN; i += (size_t)gridDim.x * 256) {
    size_t e = i * 4;
    us4 a = *(const us4*)(part + e);
    us4 b = *(const us4*)(part + MN + e);
    f32x4 bb = *(const f32x4*)(bias + (int)(e % FFN_));
    us4 o;
#pragma unroll
    for (int j = 0; j < 4; ++j) {
      float t = b2f(a[j]) + b2f(b[j]) + bb[j];
      t = 0.5f * t * (1.f + erff(t * 0.70710678118f));
      o[j] = f2b(t);
    }
    *(us4*)(out + e) = o;
  }
}

// ---------- split-K reduce (3-way, bf16 partials): out = Σp + bias + res ----
__global__ __launch_bounds__(256) void reduce3_kernel(
    const unsigned short* __restrict__ part, const float* __restrict__ bias,
    const float* __restrict__ res, float* __restrict__ out) {
  const size_t MN = (size_t)SEQ_ * DIM_;
  for (size_t i = blockIdx.x * 256 + threadIdx.x; i * 4 < MN; i += (size_t)gridDim.x * 256) {
    size_t e = i * 4;
    us4 a = *(const us4*)(part + e);
    us4 b = *(const us4*)(part + MN + e);
    us4 c = *(const us4*)(part + 2 * MN + e);
    f32x4 r = *(const f32x4*)(res + e);
    f32x4 bb = *(const f32x4*)(bias + (int)(e % DIM_));
    f32x4 o;
#pragma unroll
    for (int j = 0; j < 4; ++j) o[j] = b2f(a[j]) + b2f(b[j]) + b2f(c[j]) + r[j] + bb[j];
    *(f32x4*)(out + e) = o;
  }
}

// ---------- fused: h = Σp+bias+res ; y = LN(h) (bf16 partials) ----------
__global__ __launch_bounds__(256) void reduce3_ln_kernel(
    const unsigned short* __restrict__ part, const float* __restrict__ bias,
    const float* __restrict__ res, const float* __restrict__ g,
    const float* __restrict__ b, float* __restrict__ hout,
    unsigned short* __restrict__ yout) {
  const size_t MN = (size_t)SEQ_ * DIM_;
  int row = blockIdx.x, tid = threadIdx.x;
  int l = tid & 63, w = tid >> 6;
  float v[5], s = 0.f, s2 = 0.f;
#pragma unroll
  for (int i = 0; i < 5; ++i) {
    int c = tid + i * 256;
    size_t e = (size_t)row * DIM_ + c;
    float t = b2f(part[e]) + b2f(part[MN + e]) + b2f(part[2 * MN + e]) + bias[c] + res[e];
    hout[e] = t;
    v[i] = t;
    s += t;
    s2 += t * t;
  }
#pragma unroll
  for (int off = 1; off < 64; off <<= 1) {
    s += __shfl_xor(s, off);
    s2 += __shfl_xor(s2, off);
  }
  __shared__ float red[8];
  if (l == 0) { red[w * 2] = s; red[w * 2 + 1] = s2; }
  __syncthreads();
  s = red[0] + red[2] + red[4] + red[6];
  s2 = red[1] + red[3] + red[5] + red[7];
  float mu = s * (1.f / DIM_);
  float var = s2 * (1.f / DIM_) - mu * mu;
  float rs = rsqrtf(var + 1e-5f);
#pragma unroll
  for (int i = 0; i < 5; ++i) {
    int c = tid + i * 256;
    yout[(size_t)row * DIM_ + c] = f2b((v[i] - mu) * rs * g[c] + b[c]);
  }
}

// ---------- attention: per (head, seg, 64-row q chunk) ----------
// S in bf16 (64KB LDS -> 2 blocks/CU); T5 setprio on MFMA clusters.
__global__ __launch_bounds__(256) void attn_kernel(
    const unsigned short* __restrict__ Q, const unsigned short* __restrict__ Kb,
    const unsigned short* __restrict__ Vt, unsigned short* __restrict__ O) {
  __shared__ unsigned short S[64][512];  // 64 KiB
  int tid = threadIdx.x;
  int l = tid & 63, w = tid >> 6;
  int orig = blockIdx.x;
  int b = (orig & 7) * (gridDim.x >> 3) + (orig >> 3);
  int qc = b & 7, seg = (b >> 3) & 7, hh = b >> 6;
  int r16 = l & 15, kg = l >> 4, rg = (l >> 4) * 4;
  int qrow0 = seg * SEG_ + qc * 64 + w * 16;
  bf16x8 aq[2];
#pragma unroll
  for (int ks = 0; ks < 2; ++ks)
    aq[ks] = *(const bf16x8*)(Q + (size_t)(qrow0 + r16) * DIM_ + hh * HDIM_ + ks * 32 + kg * 8);
#pragma unroll 4
  for (int kc = 0; kc < 32; ++kc) {
    f32x4 acc = {};
    __builtin_amdgcn_s_setprio(1);
#pragma unroll
    for (int ks = 0; ks < 2; ++ks) {
      bf16x8 bk = *(const bf16x8*)(Kb + (size_t)(seg * SEG_ + kc * 16 + r16) * DIM_ +
                                   hh * HDIM_ + ks * 32 + kg * 8);
      acc = __builtin_amdgcn_mfma_f32_16x16x32_bf16(aq[ks], bk, acc, 0, 0, 0);
    }
    __builtin_amdgcn_s_setprio(0);
#pragma unroll
    for (int j = 0; j < 4; ++j)
      S[w * 16 + rg + j][kc * 16 + r16] = f2b(acc[j] * 0.125f);
  }
#pragma unroll 2
  for (int r = 0; r < 16; ++r) {
    unsigned short* Sr = &S[w * 16 + r][0];
    us8 raw = *(const us8*)(Sr + l * 8);
    float ev[8];
#pragma unroll
    for (int j = 0; j < 8; ++j) ev[j] = b2f(raw[j]);
    float m = fmaxf(fmaxf(fmaxf(ev[0], ev[1]), fmaxf(ev[2], ev[3])),
                    fmaxf(fmaxf(ev[4], ev[5]), fmaxf(ev[6], ev[7])));
#pragma unroll
    for (int off = 1; off < 64; off <<= 1) m = fmaxf(m, __shfl_xor(m, off));
    float sum = 0.f;
#pragma unroll
    for (int j = 0; j < 8; ++j) { ev[j] = __expf(ev[j] - m); sum += ev[j]; }
#pragma unroll
    for (int off = 1; off < 64; off <<= 1) sum += __shfl_xor(sum, off);
    float inv = 1.f / sum;
    us8 pk;
#pragma unroll
    for (int j = 0; j < 8; ++j) pk[j] = f2b(ev[j] * inv);
    *(us8*)(Sr + ((l ^ (r & 7)) * 8)) = pk;
  }
  f32x4 oacc[4] = {};
  const unsigned short* Pr = &S[w * 16 + r16][0];
  int rowx = r16 & 7;
#pragma unroll 2
  for (int ks = 0; ks < 16; ++ks) {
    int chunk = (ks * 4 + kg) ^ rowx;
    bf16x8 pa = *(const bf16x8*)(Pr + chunk * 8);
    __builtin_amdgcn_s_setprio(1);
#pragma unroll
    for (int df = 0; df < 4; ++df) {
      bf16x8 bv = *(const bf16x8*)(Vt + (size_t)(hh * HDIM_ + df * 16 + r16) * SEQ_ +
                                   seg * SEG_ + ks * 32 + kg * 8);
      oacc[df] = __builtin_amdgcn_mfma_f32_16x16x32_bf16(pa, bv, oacc[df], 0, 0, 0);
    }
    __builtin_amdgcn_s_setprio(0);
  }
#pragma unroll
  for (int df = 0; df < 4; ++df)
#pragma unroll
    for (int j = 0; j < 4; ++j)
      O[(size_t)(qrow0 + rg + j) * DIM_ + hh * HDIM_ + df * 16 + r16] = f2b(oacc[df][j]);
}

extern "C" void kernel_launch(void* const* d_in, const int* in_sizes, int n_in,
                              void* d_out, int out_size, void* d_ws, size_t ws_size,
                              hipStream_t stream) {
  (void)in_sizes; (void)n_in; (void)out_size; (void)ws_size;
  const float* hidden = (const float*)d_in[0];
  const float* Wq = (const float*)d_in[2];
  const float* bq = (const float*)d_in[3];
  const float* Wk = (const float*)d_in[4];
  const float* Wv = (const float*)d_in[5];
  const float* bv = (const float*)d_in[6];
  const float* Wo = (const float*)d_in[7];
  const float* bo = (const float*)d_in[8];
  const float* g1 = (const float*)d_in[9];
  const float* b1 = (const float*)d_in[10];
  const float* Wf1 = (const float*)d_in[11];
  const float* bf1 = (const float*)d_in[12];
  const float* Wf2 = (const float*)d_in[13];
  const float* bf2 = (const float*)d_in[14];
  const float* g2 = (const float*)d_in[15];
  const float* b2 = (const float*)d_in[16];

  char* p = (char*)d_ws;
  auto alloc = [&](size_t bytes) {
    char* r = p;
    p += (bytes + 255) & ~(size_t)255;
    return r;
  };
  // NOTE alloc order: [xln..part3] forms one contiguous 83.9MB span that
  // exactly holds ffn1's [2][SEQ][FFN] bf16 partials (each buffer is a
  // multiple of 256B, 4x10.49 + 10.49 + 31.46 = 2x41.94MB). All span
  // occupants are dead before ffn1_gemm runs.
  unsigned short* Wqkvt = (unsigned short*)alloc((size_t)DIM_ * QKVN_ * 2);
  unsigned short* Wot   = (unsigned short*)alloc((size_t)DIM_ * DIM_ * 2);
  unsigned short* Wf1t  = (unsigned short*)alloc((size_t)DIM_ * FFN_ * 2);
  unsigned short* Wf2t  = (unsigned short*)alloc((size_t)DIM_ * FFN_ * 2);
  float*          hbuf  = (float*)alloc((size_t)SEQ_ * DIM_ * 4);
  unsigned short* ybuf  = (unsigned short*)alloc((size_t)SEQ_ * DIM_ * 2);
  unsigned short* gbuf  = (unsigned short*)alloc((size_t)SEQ_ * FFN_ * 2);
  unsigned short* xln   = (unsigned short*)alloc((size_t)SEQ_ * DIM_ * 2);
  unsigned short* Qb    = (unsigned short*)alloc((size_t)SEQ_ * DIM_ * 2);
  unsigned short* Kbf   = (unsigned short*)alloc((size_t)SEQ_ * DIM_ * 2);
  unsigned short* Vtb   = (unsigned short*)alloc((size_t)SEQ_ * DIM_ * 2);
  unsigned short* attnb = (unsigned short*)alloc((size_t)SEQ_ * DIM_ * 2);
  unsigned short* part3 = (unsigned short*)alloc((size_t)3 * SEQ_ * DIM_ * 2);
  unsigned short* partF = xln;  // [2][SEQ][FFN] bf16 aliases xln..part3

  // all 6 weight transposes + LN1 in one dispatch
  transp_ln_kernel<<<19200 + SEQ_, 256, 0, stream>>>(
      Wq, Wk, Wv, Wo, Wf1, Wf2, Wqkvt, Wot, Wf1t, Wf2t, hidden, g1, b1, xln);
  // QKV: 480 blocks, 40 steps
  qkv_gemm<<<dim3(QKVN_ / 256, SEQ_ / 128), 512, 0, stream>>>(
      xln, Wqkvt, bq, bv, Qb, Kbf, Vtb);
  attn_kernel<<<NHEAD_ * 8 * 8, 256, 0, stream>>>(Qb, Kbf, Vtb, attnb);
  // Wo split-K=3 (bf16 partials): 480 blocks; fused reduce+LN2 -> hbuf, ybuf
  wo_gemm<<<dim3(DIM_ / 256, SEQ_ / 128, 3), 512, 0, stream>>>(attnb, Wot, part3);
  reduce3_ln_kernel<<<SEQ_, 256, 0, stream>>>(part3, bo, hidden, g2, b2, hbuf, ybuf);
  // FFN1 split-K=2 (bf16 partials into dead span): 1280 blocks x 20 steps
  ffn1_gemm<<<dim3(FFN_ / 256, SEQ_ / 128, 2), 512, 0, stream>>>(ybuf, Wf1t, partF);
  gelu_reduce2_kernel<<<2048, 256, 0, stream>>>(partF, bf1, gbuf);
  // FFN2 split-K=3 (bf16 partials): 480 blocks; reduce -> d_out
  ffn2_gemm<<<dim3(DIM_ / 256, SEQ_ / 128, 3), 512, 0, stream>>>(gbuf, Wf2t, part3);
  reduce3_kernel<<<2048, 256, 0, stream>>>(part3, bf2, hbuf, (float*)d_out);
}

// Round 19
// 318.591 us; speedup vs baseline: 1.1915x; 1.1915x over previous
//
#include <hip/hip_runtime.h>
#include <cstdint>
#include <cstddef>

#define SEQ_ 4096
#define DIM_ 1280
#define NHEAD_ 20
#define HDIM_ 64
#define FFN_ 5120
#define SEG_ 512
#define QKVN_ 3840

typedef __attribute__((ext_vector_type(8))) short bf16x8;
typedef __attribute__((ext_vector_type(4))) float f32x4;
typedef __attribute__((ext_vector_type(8))) unsigned short us8;
typedef __attribute__((ext_vector_type(4))) unsigned short us4;

__device__ __forceinline__ unsigned short f2b(float f) {
  unsigned int u = __builtin_bit_cast(unsigned int, f);
  u += 0x7fffu + ((u >> 16) & 1u);
  return (unsigned short)(u >> 16);
}

__device__ __forceinline__ float b2f(unsigned short u) {
  return __builtin_bit_cast(float, (unsigned int)u << 16);
}

__device__ __forceinline__ void gload_lds16(const void* g, void* l) {
  __builtin_amdgcn_global_load_lds(
      (const __attribute__((address_space(1))) unsigned int*)g,
      (__attribute__((address_space(3))) unsigned int*)l, 16, 0, 0);
}

#define WAITVM(N) asm volatile("s_waitcnt vmcnt(" #N ")" ::: "memory")

// ---------- batched: 6 weight transposes (f32->bf16) + LN1, one dispatch ----
__global__ __launch_bounds__(256) void transp_ln_kernel(
    const float* __restrict__ Wq, const float* __restrict__ Wk,
    const float* __restrict__ Wv, const float* __restrict__ Wo,
    const float* __restrict__ Wf1, const float* __restrict__ Wf2,
    unsigned short* __restrict__ Wqkvt, unsigned short* __restrict__ Wot,
    unsigned short* __restrict__ Wf1t, unsigned short* __restrict__ Wf2t,
    const float* __restrict__ hidden, const float* __restrict__ g1,
    const float* __restrict__ b1, unsigned short* __restrict__ xln) {
  int t = blockIdx.x;
  if (t >= 19200) {  // ---- LN1 row ----
    int row = t - 19200, tid = threadIdx.x;
    int l = tid & 63, w = tid >> 6;
    const float* x = hidden + (size_t)row * DIM_;
    float v[5], s = 0.f, s2 = 0.f;
#pragma unroll
    for (int i = 0; i < 5; ++i) {
      v[i] = x[tid + i * 256];
      s += v[i];
      s2 += v[i] * v[i];
    }
#pragma unroll
    for (int off = 1; off < 64; off <<= 1) {
      s += __shfl_xor(s, off);
      s2 += __shfl_xor(s2, off);
    }
    __shared__ float red[8];
    if (l == 0) { red[w * 2] = s; red[w * 2 + 1] = s2; }
    __syncthreads();
    s = red[0] + red[2] + red[4] + red[6];
    s2 = red[1] + red[3] + red[5] + red[7];
    float mu = s * (1.f / DIM_);
    float var = s2 * (1.f / DIM_) - mu * mu;
    float rs = rsqrtf(var + 1e-5f);
#pragma unroll
    for (int i = 0; i < 5; ++i) {
      int c = tid + i * 256;
      xln[(size_t)row * DIM_ + c] = f2b((v[i] - mu) * rs * g1[c] + b1[c]);
    }
    return;
  }
  // ---- transpose tile ----
  __shared__ float tile[32][33];
  const float* in;
  unsigned short* out;
  int R, C, bx, by;
  if (t < 6400) {
    int m = t / 1600, lt = t - m * 1600;
    in = (m == 0) ? Wq : (m == 1) ? Wk : (m == 2) ? Wv : Wo;
    out = (m < 3) ? Wqkvt + (size_t)m * DIM_ * DIM_ : Wot;
    R = DIM_; C = DIM_;
    bx = lt % 40; by = lt / 40;
  } else if (t < 12800) {
    int lt = t - 6400;
    in = Wf1; out = Wf1t; R = DIM_; C = FFN_;
    bx = lt % 160; by = lt / 160;
  } else {
    int lt = t - 12800;
    in = Wf2; out = Wf2t; R = FFN_; C = DIM_;
    bx = lt % 40; by = lt / 40;
  }
  int c0 = bx * 32, r0 = by * 32;
  int tx = threadIdx.x & 31, ty = threadIdx.x >> 5;
#pragma unroll
  for (int i = 0; i < 32; i += 8)
    tile[ty + i][tx] = in[(size_t)(r0 + ty + i) * C + c0 + tx];
  __syncthreads();
#pragma unroll
  for (int i = 0; i < 32; i += 8)
    out[(size_t)(c0 + ty + i) * R + r0 + tx] = f2b(tile[tx][ty + i]);
}

// ---------- 128x256 GEMM, BK=32, 8 waves, 3-buffer counted-vmcnt pipeline ----
// ROUND-12 KNOWN-GOOD structure (plateau ~1.6us/block-K-step, LDS-bound).
enum { EPI_QKV = 0, EPI_GELU = 3, EPI_PART = 4 };

template <int EPI>
__device__ __forceinline__ void gemm_body(
    const unsigned short* __restrict__ A, int lda,
    const unsigned short* __restrict__ Bt, int ldb,
    const float* __restrict__ bias, const float* __restrict__ bias2,
    void* __restrict__ out0, void* __restrict__ out1, void* __restrict__ out2,
    int M, int N, int K, int nz) {
  __shared__ char lds[3][24576];
  const int tid = threadIdx.x;
  const int l = tid & 63, w = tid >> 6;
  const int r16 = l & 15, kg4 = l >> 4;
  const int nx = gridDim.x;
  const int orig = blockIdx.y * nx + blockIdx.x;
  const int xcd = orig & 7, idx = orig >> 3;
  const int by = xcd * (gridDim.y >> 3) + idx / nx;
  const int bx = idx % nx;
  const int m0 = by * 128, n0 = bx * 256;
  const int wm = (w >> 2) * 64, wn = (w & 3) * 64;
  const int z = blockIdx.z;
  const int ntK = K >> 5;
  const int base = ntK / nz, rem = ntK % nz;
  const int k0 = z * base + (z < rem ? z : rem);
  const int nt = base + (z < rem ? 1 : 0);
  const int kc = (tid & 3) ^ ((tid >> 3) & 3);
  const unsigned short* aA = A + (size_t)(m0 + (tid >> 2)) * lda + kc * 8 + k0 * 32;
  const unsigned short* aB = Bt + (size_t)(n0 + (tid >> 2)) * ldb + kc * 8 + k0 * 32;
  const unsigned short* aB1 = aB + (size_t)128 * ldb;
  const int cswz = (kg4 ^ ((r16 >> 1) & 3)) << 4;
  int aoff[4], boff[4];
#pragma unroll
  for (int mi = 0; mi < 4; ++mi) aoff[mi] = (wm + mi * 16 + r16) * 64 + cswz;
#pragma unroll
  for (int ni = 0; ni < 4; ++ni) boff[ni] = 8192 + (wn + ni * 16 + r16) * 64 + cswz;

  f32x4 acc[4][4] = {};

#define STAGE(b, kt_)                                          \
  do {                                                         \
    const int kb = (kt_) * 32;                                 \
    char* dA = &lds[0][0] + (b) * 24576 + w * 1024;            \
    char* dB = dA + 8192;                                      \
    gload_lds16(aA + kb, dA);                                  \
    gload_lds16(aB + kb, dB);                                  \
    gload_lds16(aB1 + kb, dB + 8192);                          \
  } while (0)

  STAGE(0, 0);
  if (nt > 1) {
    STAGE(1, 1);
    WAITVM(3);
  } else {
    WAITVM(0);
  }
  __builtin_amdgcn_s_barrier();

  int cur = 0;
#pragma unroll 1
  for (int t = 0; t < nt; ++t) {
    if (t + 2 < nt) {
      int nxt = cur + 2; if (nxt >= 3) nxt -= 3;
      STAGE(nxt, t + 2);
    }
    const char* sl = &lds[0][0] + cur * 24576;
    bf16x8 af[4], bfv[4];
#pragma unroll
    for (int mi = 0; mi < 4; ++mi) af[mi] = *(const bf16x8*)(sl + aoff[mi]);
#pragma unroll
    for (int ni = 0; ni < 4; ++ni) bfv[ni] = *(const bf16x8*)(sl + boff[ni]);
    __builtin_amdgcn_s_setprio(1);
#pragma unroll
    for (int mi = 0; mi < 4; ++mi)
#pragma unroll
      for (int ni = 0; ni < 4; ++ni)
        acc[mi][ni] = __builtin_amdgcn_mfma_f32_16x16x32_bf16(af[mi], bfv[ni], acc[mi][ni], 0, 0, 0);
    __builtin_amdgcn_s_setprio(0);
    if (t + 2 < nt) WAITVM(3);
    else if (t + 1 < nt) WAITVM(0);
    if (t + 1 < nt) __builtin_amdgcn_s_barrier();
    ++cur; if (cur == 3) cur = 0;
  }
#undef STAGE

  const int rg = kg4 * 4;
#pragma unroll
  for (int mi = 0; mi < 4; ++mi) {
#pragma unroll
    for (int ni = 0; ni < 4; ++ni) {
      int row = m0 + wm + mi * 16 + rg;
      int col = n0 + wn + ni * 16 + r16;
      f32x4 v = acc[mi][ni];
      if constexpr (EPI == EPI_QKV) {
        if (col < DIM_) {  // Q (+bq)
          unsigned short* O = (unsigned short*)out0;
          float bb = bias[col];
#pragma unroll
          for (int j = 0; j < 4; ++j) O[(size_t)(row + j) * DIM_ + col] = f2b(v[j] + bb);
        } else if (col < 2 * DIM_) {  // K (no bias)
          unsigned short* O = (unsigned short*)out1;
          int cc = col - DIM_;
#pragma unroll
          for (int j = 0; j < 4; ++j) O[(size_t)(row + j) * DIM_ + cc] = f2b(v[j]);
        } else {  // V (+bv), transposed -> Vt[d][s]
          unsigned short* O = (unsigned short*)out2;
          int cc = col - 2 * DIM_;
          float bb = bias2[cc];
          us4 pk;
#pragma unroll
          for (int j = 0; j < 4; ++j) pk[j] = f2b(v[j] + bb);
          *(us4*)(O + (size_t)cc * SEQ_ + row) = pk;
        }
      } else if constexpr (EPI == EPI_GELU) {
        unsigned short* O = (unsigned short*)out0;
        float bb = bias[col];
#pragma unroll
        for (int j = 0; j < 4; ++j) {
          float t = v[j] + bb;
          t = 0.5f * t * (1.f + erff(t * 0.70710678118f));
          O[(size_t)(row + j) * N + col] = f2b(t);
        }
      } else {  // EPI_PART: bf16 partial per K-split
        unsigned short* O = (unsigned short*)out0 + (size_t)blockIdx.z * M * N;
#pragma unroll
        for (int j = 0; j < 4; ++j) O[(size_t)(row + j) * N + col] = f2b(v[j]);
      }
    }
  }
}

// distinct names for rocprof attribution
__global__ __launch_bounds__(512, 4) void qkv_gemm(
    const unsigned short* A, const unsigned short* Bt, const float* bq,
    const float* bv, void* q, void* k, void* v) {
  gemm_body<EPI_QKV>(A, DIM_, Bt, DIM_, bq, bv, q, k, v, SEQ_, QKVN_, DIM_, 1);
}
__global__ __launch_bounds__(512, 4) void wo_gemm(
    const unsigned short* A, const unsigned short* Bt, void* part) {
  gemm_body<EPI_PART>(A, DIM_, Bt, DIM_, nullptr, nullptr, part, nullptr, nullptr,
                      SEQ_, DIM_, DIM_, 3);
}
__global__ __launch_bounds__(512, 4) void ffn1_gemm(
    const unsigned short* A, const unsigned short* Bt, const float* bf1, void* g) {
  gemm_body<EPI_GELU>(A, DIM_, Bt, DIM_, bf1, nullptr, g, nullptr, nullptr,
                      SEQ_, FFN_, DIM_, 1);
}
__global__ __launch_bounds__(512, 4) void ffn2_gemm(
    const unsigned short* A, const unsigned short* Bt, void* part) {
  gemm_body<EPI_PART>(A, FFN_, Bt, FFN_, nullptr, nullptr, part, nullptr, nullptr,
                      SEQ_, DIM_, FFN_, 3);
}

// ---------- split-K reduce (3-way, bf16 partials): out = Σp + bias + res ----
__global__ __launch_bounds__(256) void reduce3_kernel(
    const unsigned short* __restrict__ part, const float* __restrict__ bias,
    const float* __restrict__ res, float* __restrict__ out) {
  const size_t MN = (size_t)SEQ_ * DIM_;
  for (size_t i = blockIdx.x * 256 + threadIdx.x; i * 4 < MN; i += (size_t)gridDim.x * 256) {
    size_t e = i * 4;
    us4 a = *(const us4*)(part + e);
    us4 b = *(const us4*)(part + MN + e);
    us4 c = *(const us4*)(part + 2 * MN + e);
    f32x4 r = *(const f32x4*)(res + e);
    f32x4 bb = *(const f32x4*)(bias + (int)(e % DIM_));
    f32x4 o;
#pragma unroll
    for (int j = 0; j < 4; ++j) o[j] = b2f(a[j]) + b2f(b[j]) + b2f(c[j]) + r[j] + bb[j];
    *(f32x4*)(out + e) = o;
  }
}

// ---------- fused: h = Σp+bias+res ; y = LN(h) (bf16 partials) ----------
__global__ __launch_bounds__(256) void reduce3_ln_kernel(
    const unsigned short* __restrict__ part, const float* __restrict__ bias,
    const float* __restrict__ res, const float* __restrict__ g,
    const float* __restrict__ b, float* __restrict__ hout,
    unsigned short* __restrict__ yout) {
  const size_t MN = (size_t)SEQ_ * DIM_;
  int row = blockIdx.x, tid = threadIdx.x;
  int l = tid & 63, w = tid >> 6;
  float v[5], s = 0.f, s2 = 0.f;
#pragma unroll
  for (int i = 0; i < 5; ++i) {
    int c = tid + i * 256;
    size_t e = (size_t)row * DIM_ + c;
    float t = b2f(part[e]) + b2f(part[MN + e]) + b2f(part[2 * MN + e]) + bias[c] + res[e];
    hout[e] = t;
    v[i] = t;
    s += t;
    s2 += t * t;
  }
#pragma unroll
  for (int off = 1; off < 64; off <<= 1) {
    s += __shfl_xor(s, off);
    s2 += __shfl_xor(s2, off);
  }
  __shared__ float red[8];
  if (l == 0) { red[w * 2] = s; red[w * 2 + 1] = s2; }
  __syncthreads();
  s = red[0] + red[2] + red[4] + red[6];
  s2 = red[1] + red[3] + red[5] + red[7];
  float mu = s * (1.f / DIM_);
  float var = s2 * (1.f / DIM_) - mu * mu;
  float rs = rsqrtf(var + 1e-5f);
#pragma unroll
  for (int i = 0; i < 5; ++i) {
    int c = tid + i * 256;
    yout[(size_t)row * DIM_ + c] = f2b((v[i] - mu) * rs * g[c] + b[c]);
  }
}

// ---------- attention v3: LDS-staged K/V (coalesced, deduped) ----------
// Per block (head,seg,64 q-rows): K/V tiles staged through a shared 16KB
// buffer in 4 chunks each (rule-#21 XOR chunk swizzle: pre-swizzled global
// source, linear gload dest, swizzled ds_read -> bank-balanced). Removes the
// ~16x uncoalesced L2 line traffic AND the 4x inter-wave tile re-read that
// made round-18's attn 113us (MfmaUtil 3.7%, HBM 2.9%). S in bf16 (64KB);
// total LDS 80KB -> 2 blocks/CU.
__global__ __launch_bounds__(256) void attn_kernel(
    const unsigned short* __restrict__ Q, const unsigned short* __restrict__ Kb,
    const unsigned short* __restrict__ Vt, unsigned short* __restrict__ O) {
  __shared__ unsigned short S[64][512];  // 64 KiB
  __shared__ unsigned short KV[8192];    // 16 KiB staging (K chunks, then V)
  int tid = threadIdx.x;
  int l = tid & 63, w = tid >> 6;
  int orig = blockIdx.x;
  int b = (orig & 7) * (gridDim.x >> 3) + (orig >> 3);
  int qc = b & 7, seg = (b >> 3) & 7, hh = b >> 6;
  int r16 = l & 15, kg = l >> 4, rg = (l >> 4) * 4;
  int qrow0 = seg * SEG_ + qc * 64 + w * 16;
  bf16x8 aq[2];
#pragma unroll
  for (int ks = 0; ks < 2; ++ks)
    aq[ks] = *(const bf16x8*)(Q + (size_t)(qrow0 + r16) * DIM_ + hh * HDIM_ + ks * 32 + kg * 8);
  // ---- QK^T: 4 chunks of 128 K-rows ----
#pragma unroll 1
  for (int kcc = 0; kcc < 4; ++kcc) {
    __syncthreads();  // prior chunk fully consumed by all waves
#pragma unroll
    for (int i = 0; i < 4; ++i) {
      int slot = i * 256 + tid;          // 1024 slots x 16B
      int r = slot >> 3, cp = slot & 7;  // row 0..127, phys chunk
      int kc = cp ^ (r & 7);             // logical 8-dim chunk
      gload_lds16(Kb + (size_t)(seg * SEG_ + kcc * 128 + r) * DIM_ + hh * HDIM_ + kc * 8,
                  (char*)KV + slot * 16);
    }
    WAITVM(0);
    __syncthreads();
#pragma unroll
    for (int kcl = 0; kcl < 8; ++kcl) {
      f32x4 acc = {};
      __builtin_amdgcn_s_setprio(1);
#pragma unroll
      for (int ks = 0; ks < 2; ++ks) {
        int c = ks * 4 + kg;
        bf16x8 bk = *(const bf16x8*)((const char*)KV +
                      ((kcl * 16 + r16) * 8 + (c ^ (r16 & 7))) * 16);
        acc = __builtin_amdgcn_mfma_f32_16x16x32_bf16(aq[ks], bk, acc, 0, 0, 0);
      }
      __builtin_amdgcn_s_setprio(0);
      int kcg = kcc * 8 + kcl;
#pragma unroll
      for (int j = 0; j < 4; ++j)
        S[w * 16 + rg + j][kcg * 16 + r16] = f2b(acc[j] * 0.125f);
    }
  }
  // ---- softmax (per-wave rows; own-wave S only, no barrier needed) ----
#pragma unroll 2
  for (int r = 0; r < 16; ++r) {
    unsigned short* Sr = &S[w * 16 + r][0];
    us8 raw = *(const us8*)(Sr + l * 8);
    float ev[8];
#pragma unroll
    for (int j = 0; j < 8; ++j) ev[j] = b2f(raw[j]);
    float m = fmaxf(fmaxf(fmaxf(ev[0], ev[1]), fmaxf(ev[2], ev[3])),
                    fmaxf(fmaxf(ev[4], ev[5]), fmaxf(ev[6], ev[7])));
#pragma unroll
    for (int off = 1; off < 64; off <<= 1) m = fmaxf(m, __shfl_xor(m, off));
    float sum = 0.f;
#pragma unroll
    for (int j = 0; j < 8; ++j) { ev[j] = __expf(ev[j] - m); sum += ev[j]; }
#pragma unroll
    for (int off = 1; off < 64; off <<= 1) sum += __shfl_xor(sum, off);
    float inv = 1.f / sum;
    us8 pk;
#pragma unroll
    for (int j = 0; j < 8; ++j) pk[j] = f2b(ev[j] * inv);
    *(us8*)(Sr + ((l ^ (r & 7)) * 8)) = pk;
  }
  // ---- PV: 4 chunks of 128 s-cols (V staged into same buffer) ----
  f32x4 oacc[4] = {};
  const unsigned short* Pr = &S[w * 16 + r16][0];
  int rowx = r16 & 7;
#pragma unroll 1
  for (int vcc = 0; vcc < 4; ++vcc) {
    __syncthreads();  // all waves past last KV use (K chunk 3 / prior V chunk)
#pragma unroll
    for (int i = 0; i < 4; ++i) {
      int slot = i * 256 + tid;            // 1024 slots x 16B
      int r = slot >> 4, cp = slot & 15;   // d-row 0..63, phys chunk 0..15
      int kc = (cp & 8) | ((cp & 7) ^ (r & 7));
      gload_lds16(Vt + (size_t)(hh * HDIM_ + r) * SEQ_ + seg * SEG_ + vcc * 128 + kc * 8,
                  (char*)KV + slot * 16);
    }
    WAITVM(0);
    __syncthreads();
#pragma unroll
    for (int ksl = 0; ksl < 4; ++ksl) {
      int ks = vcc * 4 + ksl;
      int chunk = (ks * 4 + kg) ^ rowx;
      bf16x8 pa = *(const bf16x8*)(Pr + chunk * 8);
      __builtin_amdgcn_s_setprio(1);
#pragma unroll
      for (int df = 0; df < 4; ++df) {
        int vr = df * 16 + r16;
        int c = ksl * 4 + kg;
        int cp = (c & 8) | ((c & 7) ^ (vr & 7));
        bf16x8 bv = *(const bf16x8*)((const char*)KV + (vr * 16 + cp) * 16);
        oacc[df] = __builtin_amdgcn_mfma_f32_16x16x32_bf16(pa, bv, oacc[df], 0, 0, 0);
      }
      __builtin_amdgcn_s_setprio(0);
    }
  }
#pragma unroll
  for (int df = 0; df < 4; ++df)
#pragma unroll
    for (int j = 0; j < 4; ++j)
      O[(size_t)(qrow0 + rg + j) * DIM_ + hh * HDIM_ + df * 16 + r16] = f2b(oacc[df][j]);
}

extern "C" void kernel_launch(void* const* d_in, const int* in_sizes, int n_in,
                              void* d_out, int out_size, void* d_ws, size_t ws_size,
                              hipStream_t stream) {
  (void)in_sizes; (void)n_in; (void)out_size; (void)ws_size;
  const float* hidden = (const float*)d_in[0];
  const float* Wq = (const float*)d_in[2];
  const float* bq = (const float*)d_in[3];
  const float* Wk = (const float*)d_in[4];
  const float* Wv = (const float*)d_in[5];
  const float* bv = (const float*)d_in[6];
  const float* Wo = (const float*)d_in[7];
  const float* bo = (const float*)d_in[8];
  const float* g1 = (const float*)d_in[9];
  const float* b1 = (const float*)d_in[10];
  const float* Wf1 = (const float*)d_in[11];
  const float* bf1 = (const float*)d_in[12];
  const float* Wf2 = (const float*)d_in[13];
  const float* bf2 = (const float*)d_in[14];
  const float* g2 = (const float*)d_in[15];
  const float* b2 = (const float*)d_in[16];

  char* p = (char*)d_ws;
  auto alloc = [&](size_t bytes) {
    char* r = p;
    p += (bytes + 255) & ~(size_t)255;
    return r;
  };
  unsigned short* xln   = (unsigned short*)alloc((size_t)SEQ_ * DIM_ * 2);
  unsigned short* Wqkvt = (unsigned short*)alloc((size_t)DIM_ * QKVN_ * 2);
  unsigned short* Wot   = (unsigned short*)alloc((size_t)DIM_ * DIM_ * 2);
  unsigned short* Wf1t  = (unsigned short*)alloc((size_t)DIM_ * FFN_ * 2);
  unsigned short* Wf2t  = (unsigned short*)alloc((size_t)DIM_ * FFN_ * 2);
  unsigned short* Qb    = (unsigned short*)alloc((size_t)SEQ_ * DIM_ * 2);
  unsigned short* Kbf   = (unsigned short*)alloc((size_t)SEQ_ * DIM_ * 2);
  unsigned short* Vtb   = (unsigned short*)alloc((size_t)SEQ_ * DIM_ * 2);
  unsigned short* attnb = (unsigned short*)alloc((size_t)SEQ_ * DIM_ * 2);
  float*          hbuf  = (float*)alloc((size_t)SEQ_ * DIM_ * 4);
  unsigned short* ybuf  = (unsigned short*)alloc((size_t)SEQ_ * DIM_ * 2);
  unsigned short* gbuf  = (unsigned short*)alloc((size_t)SEQ_ * FFN_ * 2);
  unsigned short* part3 = (unsigned short*)alloc((size_t)3 * SEQ_ * DIM_ * 2);

  // all 6 weight transposes + LN1 in one dispatch
  transp_ln_kernel<<<19200 + SEQ_, 256, 0, stream>>>(
      Wq, Wk, Wv, Wo, Wf1, Wf2, Wqkvt, Wot, Wf1t, Wf2t, hidden, g1, b1, xln);
  // QKV: 480 blocks
  qkv_gemm<<<dim3(QKVN_ / 256, SEQ_ / 128), 512, 0, stream>>>(
      xln, Wqkvt, bq, bv, Qb, Kbf, Vtb);
  attn_kernel<<<NHEAD_ * 8 * 8, 256, 0, stream>>>(Qb, Kbf, Vtb, attnb);
  // Wo split-K=3 (bf16 partials): 480 blocks; fused reduce+LN2 -> hbuf, ybuf
  wo_gemm<<<dim3(DIM_ / 256, SEQ_ / 128, 3), 512, 0, stream>>>(attnb, Wot, part3);
  reduce3_ln_kernel<<<SEQ_, 256, 0, stream>>>(part3, bo, hidden, g2, b2, hbuf, ybuf);
  // FFN1 + GELU: 640 blocks (round-17 config; split-K regressed in round 18)
  ffn1_gemm<<<dim3(FFN_ / 256, SEQ_ / 128), 512, 0, stream>>>(ybuf, Wf1t, bf1, gbuf);
  // FFN2 split-K=3 (bf16 partials): 480 blocks; reduce -> d_out
  ffn2_gemm<<<dim3(DIM_ / 256, SEQ_ / 128, 3), 512, 0, stream>>>(gbuf, Wf2t, part3);
  reduce3_kernel<<<2048, 256, 0, stream>>>(part3, bf2, hbuf, (float*)d_out);
}